// Round 10
// baseline (179.460 us; speedup 1.0000x reference)
//
#include <hip/hip_runtime.h>
#include <hip/hip_bf16.h>

typedef unsigned short u16;
typedef unsigned int u32;

constexpr int B  = 8;
constexpr int S  = 1024;
constexpr int C  = 512;
constexpr int H  = 8;
constexpr int DH = 64;     // C / H
constexpr int M  = B * S;  // 8192 rows

typedef __attribute__((ext_vector_type(8))) short bf16x8;   // 8 bf16 = 4 VGPRs
typedef __attribute__((ext_vector_type(4))) float f32x4;    // MFMA C/D

#define GLOBAL_AS __attribute__((address_space(1)))
#define LDS_AS    __attribute__((address_space(3)))

// 0.125 (1/sqrt(DH)) * log2(e): QK^T softmax runs in the exp2 domain.
#define QSCALE 0.1803368867f

__device__ __forceinline__ u16 f2bf(float f) {
    u32 u = __float_as_uint(f);
    u += 0x7fffu + ((u >> 16) & 1u);
    return (u16)(u >> 16);
}
__device__ __forceinline__ void async_cp16(const u16* g, u16* l) {
    __builtin_amdgcn_global_load_lds((const GLOBAL_AS void*)g, (LDS_AS void*)l, 16, 0, 0);
}
// load 8 f32 from g, convert to 8 bf16 (RNE, packed cvt), store 16 B to LDS
__device__ __forceinline__ void cvt_store8(u16* lds, const float* g) {
    const float4 a = *(const float4*)g;
    const float4 b = *(const float4*)(g + 4);
    __hip_bfloat162 p0 = __float22bfloat162_rn(make_float2(a.x, a.y));
    __hip_bfloat162 p1 = __float22bfloat162_rn(make_float2(a.z, a.w));
    __hip_bfloat162 p2 = __float22bfloat162_rn(make_float2(b.x, b.y));
    __hip_bfloat162 p3 = __float22bfloat162_rn(make_float2(b.z, b.w));
    uint4 o;
    o.x = *reinterpret_cast<u32*>(&p0);
    o.y = *reinterpret_cast<u32*>(&p1);
    o.z = *reinterpret_cast<u32*>(&p2);
    o.w = *reinterpret_cast<u32*>(&p3);
    *(uint4*)lds = o;
}

// ---------------------------------------------------------------------------
// Fused QKV MFMA GEMM (two-barrier m97 structure, proven R3-R8). Inputs are
// RAW f32 x and f32 Wq/Wk/Wv; staging converts to bf16 in-flight (packed
// cvt + ds_write_b128) -- no separate conversion pass. N-tiles 0..3 -> Q,
// 4..7 -> K, 8..11 -> V. Q epilogue folds QSCALE. Epilogues re-block through
// LDS and store coalesced dwordx4: Q,K -> [B,S,C]; V -> [B,H,DH,S].
// ---------------------------------------------------------------------------
__global__ __launch_bounds__(256) void qkv_gemm(
    const float* __restrict__ x,
    const float* __restrict__ wq, const float* __restrict__ wk,
    const float* __restrict__ wv,
    const float* __restrict__ bq, const float* __restrict__ bk,
    const float* __restrict__ bv,
    u16* __restrict__ Qo, u16* __restrict__ Ko, u16* __restrict__ Vo)
{
    __shared__ alignas(16) u16 smem[128 * 136];   // Asm|Bsm (16K u16) / epi tile
    u16* const Asm = smem;                        // [128][64]
    u16* const Bsm = smem + 128 * 64;             // [128][64]

    const int mTile = blockIdx.x * 128;
    const int nTile = blockIdx.y * 128;           // within 1536
    const int t = threadIdx.x, lane = t & 63, w = t >> 6;
    const int ql = lane & 15, quad = lane >> 4;
    const int wm = (w & 1) * 64, wn = (w >> 1) * 64;

    const int z = nTile >> 9;                     // 0:Q 1:K 2:V (block-uniform)
    const int nBase = nTile & 511;
    const float* Wsrc = (z == 0) ? wq : (z == 1) ? wk : wv;

    f32x4 acc[4][4];
    #pragma unroll
    for (int i = 0; i < 4; i++)
        #pragma unroll
        for (int j = 0; j < 4; j++) acc[i][j] = (f32x4){0.f, 0.f, 0.f, 0.f};

    for (int k0 = 0; k0 < C; k0 += 64) {
        __syncthreads();
        #pragma unroll
        for (int q = 0; q < 4; q++) {
            const int chunk = q * 256 + t;           // 0..1023 16B chunks
            const int row = chunk >> 3, c8 = (chunk & 7) * 8;
            cvt_store8(&Asm[chunk * 8], x    + (size_t)(mTile + row) * C + k0 + c8);
            cvt_store8(&Bsm[chunk * 8], Wsrc + (size_t)(nBase + row) * C + k0 + c8);
        }
        __syncthreads();

        #pragma unroll
        for (int ks = 0; ks < 64; ks += 32) {
            bf16x8 af[4], bfr[4];
            #pragma unroll
            for (int i = 0; i < 4; i++)
                af[i] = *(const bf16x8*)&Asm[(wm + i*16 + ql) * 64 + ks + quad*8];
            #pragma unroll
            for (int j = 0; j < 4; j++)
                bfr[j] = *(const bf16x8*)&Bsm[(wn + j*16 + ql) * 64 + ks + quad*8];
            #pragma unroll
            for (int i = 0; i < 4; i++)
                #pragma unroll
                for (int j = 0; j < 4; j++)
                    acc[i][j] = __builtin_amdgcn_mfma_f32_16x16x32_bf16(af[i], bfr[j], acc[i][j], 0, 0, 0);
        }
    }

    const float* bias = (z == 0) ? bq : (z == 1) ? bk : bv;
    const float sc    = (z == 0) ? QSCALE : 1.0f;

    // ---- fragments -> LDS tile (Q,K: [m][n]; V: transposed [n][m])
    __syncthreads();                             // done with Asm/Bsm
    u16* const T = smem;                         // [128][136]
    #pragma unroll
    for (int j = 0; j < 4; j++) {
        const int n = wn + j*16 + ql;
        const float bj = bias[nBase + n];
        #pragma unroll
        for (int i = 0; i < 4; i++) {
            #pragma unroll
            for (int r = 0; r < 4; r++) {
                const int m = wm + i*16 + quad*4 + r;
                const u16 val = f2bf((acc[i][j][r] + bj) * sc);
                if (z == 2) T[n * 136 + m] = val;
                else        T[m * 136 + n] = val;
            }
        }
    }
    __syncthreads();

    // ---- coalesced dwordx4 stores (8 chunks/thread)
    if (z == 2) {
        const int bb = mTile >> 10, ssBase = mTile & 1023;
        #pragma unroll
        for (int q = 0; q < 8; q++) {
            const int c = q * 256 + t;           // 0..2047 16B chunks
            const int row = c >> 4, col = (c & 15) * 8;     // row=n, col=m(s)
            const int o = nBase + row, h = o >> 6, d = o & 63;
            *(float4*)(Vo + ((size_t)((bb*H + h) * DH + d)) * S + ssBase + col) =
                *(const float4*)&T[row * 136 + col];
        }
    } else {
        u16* dst = (z == 0) ? Qo : Ko;
        #pragma unroll
        for (int q = 0; q < 8; q++) {
            const int c = q * 256 + t;
            const int row = c >> 4, col = (c & 15) * 8;     // row=m, col=n
            *(float4*)(dst + (size_t)(mTile + row) * C + nBase + col) =
                *(const float4*)&T[row * 136 + col];
        }
    }
}

// ---------------------------------------------------------------------------
// MFMA flash attention (exact proven R8 version). 512 threads = 8 waves per
// block, 128 q-rows per block; grid 512, XCD-swizzled. K/V tiles staged by
// global_load_lds with GLOBAL-side XOR chunk swizzle (LDS side stays linear
// = DMA-conformant; fragment reads conflict-free). No-max exp2 softmax;
// denominator via ones-column MFMA. Two barriers per k-tile.
// ---------------------------------------------------------------------------
__global__ __launch_bounds__(512) void attn_kernel(
    const u16* __restrict__ Qo,   // [B,S,C]  (pre-scaled by QSCALE)
    const u16* __restrict__ Ko,   // [B,S,C]
    const u16* __restrict__ Vo,   // [B,H,DH,S]
    u16* __restrict__ ctx)        // [B,S,C] bf16
{
    __shared__ alignas(16) u16 KsU[64 * 64];    // [key][d], global-XOR-swizzled
    __shared__ alignas(16) u16 VsU[64 * 64];    // [d][key], global-XOR-swizzled
    __shared__ alignas(16) u16 Ps [128 * 72];   // [q][key], stride 72 (padded)

    const int g = blockIdx.x;            // 0..511
    const int xcd = g & 7, slot = g >> 3;       // slot 0..63
    const int bh = xcd * 8 + (slot >> 3);       // 8 heads per XCD
    const int qt = slot & 7;                    // 128-row q tile
    const int b_ = bh >> 3, h = bh & 7;

    const int t = threadIdx.x;
    const int lane = t & 63, w = t >> 6;        // w 0..7
    const int ql = lane & 15, quad = lane >> 4;

    const u16* Qb = Qo + (size_t)b_ * S * C + h * DH;   // row stride C
    const u16* Kb = Ko + (size_t)b_ * S * C + h * DH;   // row stride C
    const u16* Vt = Vo + (size_t)bh * DH * S;

    const int qrow = qt*128 + w*16 + ql;
    const bf16x8 qf0 = *(const bf16x8*)(Qb + (size_t)qrow * C + quad*8);
    const bf16x8 qf1 = *(const bf16x8*)(Qb + (size_t)qrow * C + 32 + quad*8);

    bf16x8 onesf;
    #pragma unroll
    for (int i = 0; i < 8; i++) onesf[i] = (short)0x3F80;   // bf16 1.0

    // swizzled chunk offsets for fragment reads (row&7 == ql&7 for all reads)
    const int swzA = ((quad       ^ (ql & 7)) << 3);   // cc = quad
    const int swzB = (((quad + 4) ^ (ql & 7)) << 3);   // cc = quad + 4

    // staging: thread t handles 16B chunk t of K and of V; DMA LDS dest is
    // linear (chunk*16B); the XOR swizzle is applied to the GLOBAL chunk.
    const int srow = t >> 3, scc = t & 7;
    const int sgc8 = ((scc ^ (srow & 7)) << 3);        // swizzled global column

    f32x4 acc[4], accl;
    #pragma unroll
    for (int dt = 0; dt < 4; dt++) acc[dt] = (f32x4){0.f, 0.f, 0.f, 0.f};
    accl = (f32x4){0.f, 0.f, 0.f, 0.f};

    for (int k0 = 0; k0 < S; k0 += 64) {
        __syncthreads();
        async_cp16(Kb + (size_t)(k0 + srow) * C + sgc8, &KsU[t * 8]);
        async_cp16(Vt + (size_t)srow * S + k0 + sgc8,   &VsU[t * 8]);
        __syncthreads();

        // ---- QK^T (exp2-scaled via Q)
        f32x4 sc[4];
        #pragma unroll
        for (int nt = 0; nt < 4; nt++) {
            sc[nt] = (f32x4){0.f, 0.f, 0.f, 0.f};
            const bf16x8 kf0 = *(const bf16x8*)&KsU[(nt*16 + ql) * 64 + swzA];
            const bf16x8 kf1 = *(const bf16x8*)&KsU[(nt*16 + ql) * 64 + swzB];
            sc[nt] = __builtin_amdgcn_mfma_f32_16x16x32_bf16(qf0, kf0, sc[nt], 0, 0, 0);
            sc[nt] = __builtin_amdgcn_mfma_f32_16x16x32_bf16(qf1, kf1, sc[nt], 0, 0, 0);
        }

        // ---- softmax numerators: p = exp2(s), no max subtraction
        #pragma unroll
        for (int r = 0; r < 4; r++) {
            const int prow = w*16 + quad*4 + r;
            Ps[prow * 72 +  0 + ql] = f2bf(exp2f(sc[0][r]));
            Ps[prow * 72 + 16 + ql] = f2bf(exp2f(sc[1][r]));
            Ps[prow * 72 + 32 + ql] = f2bf(exp2f(sc[2][r]));
            Ps[prow * 72 + 48 + ql] = f2bf(exp2f(sc[3][r]));
        }

        // ---- PV + denominator (wave-private Ps stripe, wave-synchronous)
        #pragma unroll
        for (int c = 0; c < 2; c++) {
            const bf16x8 pf = *(const bf16x8*)&Ps[(w*16 + ql) * 72 + c*32 + quad*8];
            const int swz = (c == 0) ? swzA : swzB;
            #pragma unroll
            for (int dt = 0; dt < 4; dt++) {
                const bf16x8 vf = *(const bf16x8*)&VsU[(dt*16 + ql) * 64 + swz];
                acc[dt] = __builtin_amdgcn_mfma_f32_16x16x32_bf16(pf, vf, acc[dt], 0, 0, 0);
            }
            accl = __builtin_amdgcn_mfma_f32_16x16x32_bf16(pf, onesf, accl, 0, 0, 0);
        }
    }

    #pragma unroll
    for (int r = 0; r < 4; r++) {
        const float inv = 1.0f / accl[r];
        const int orow = qt*128 + w*16 + quad*4 + r;
        const size_t base = ((size_t)(b_*S + orow)) * C + h*DH;
        #pragma unroll
        for (int dt = 0; dt < 4; dt++)
            ctx[base + dt*16 + ql] = f2bf(acc[dt][r] * inv);
    }
}

// ---------------------------------------------------------------------------
// Output-projection MFMA GEMM: out = ctx @ Wo^T + bo + skip (f32 epilogue).
// 64x128 tile -> grid 512 (2 blocks/CU), two-barrier single-buffer staging.
// A (ctx, bf16) via global_load_lds DMA; B (Wo, f32) converted in staging.
// ---------------------------------------------------------------------------
__global__ __launch_bounds__(256) void out_gemm(
    const u16* __restrict__ ctx, const float* __restrict__ wo,
    const float* __restrict__ bo, const float* __restrict__ skip,
    float* __restrict__ out)
{
    __shared__ alignas(16) u16 Ab[64 * 64];     // 8 KB
    __shared__ alignas(16) u16 Bb[128 * 64];    // 16 KB

    const int mTile = blockIdx.x * 64;
    const int nTile = blockIdx.y * 128;
    const int t = threadIdx.x, lane = t & 63, w = t >> 6;
    const int ql = lane & 15, quad = lane >> 4;
    const int wm = (w & 1) * 32, wn = (w >> 1) * 64;

    f32x4 acc[2][4];
    #pragma unroll
    for (int i = 0; i < 2; i++)
        #pragma unroll
        for (int j = 0; j < 4; j++) acc[i][j] = (f32x4){0.f, 0.f, 0.f, 0.f};

    for (int k0 = 0; k0 < C; k0 += 64) {
        __syncthreads();
        #pragma unroll
        for (int q = 0; q < 2; q++) {            // A: 512 chunks (bf16 DMA)
            const int chunk = q * 256 + t;
            const int row = chunk >> 3, c8 = (chunk & 7) * 8;
            async_cp16(ctx + (size_t)(mTile + row) * C + k0 + c8, &Ab[chunk * 8]);
        }
        #pragma unroll
        for (int q = 0; q < 4; q++) {            // B: 1024 chunks (f32 -> bf16)
            const int chunk = q * 256 + t;
            const int row = chunk >> 3, c8 = (chunk & 7) * 8;
            cvt_store8(&Bb[chunk * 8], wo + (size_t)(nTile + row) * C + k0 + c8);
        }
        __syncthreads();

        #pragma unroll
        for (int ks = 0; ks < 64; ks += 32) {
            bf16x8 af[2], bfr[4];
            #pragma unroll
            for (int i = 0; i < 2; i++)
                af[i] = *(const bf16x8*)&Ab[(wm + i*16 + ql) * 64 + ks + quad*8];
            #pragma unroll
            for (int j = 0; j < 4; j++)
                bfr[j] = *(const bf16x8*)&Bb[(wn + j*16 + ql) * 64 + ks + quad*8];
            #pragma unroll
            for (int i = 0; i < 2; i++)
                #pragma unroll
                for (int j = 0; j < 4; j++)
                    acc[i][j] = __builtin_amdgcn_mfma_f32_16x16x32_bf16(af[i], bfr[j], acc[i][j], 0, 0, 0);
        }
    }

    #pragma unroll
    for (int j = 0; j < 4; j++) {
        const int o = nTile + wn + j*16 + ql;
        const float bj = bo[o];
        #pragma unroll
        for (int i = 0; i < 2; i++) {
            #pragma unroll
            for (int r = 0; r < 4; r++) {
                const int m = mTile + wm + i*16 + quad*4 + r;
                const size_t idx = (size_t)m * C + o;
                out[idx] = acc[i][j][r] + bj + skip[idx];
            }
        }
    }
}

extern "C" void kernel_launch(void* const* d_in, const int* in_sizes, int n_in,
                              void* d_out, int out_size, void* d_ws, size_t ws_size,
                              hipStream_t stream) {
    (void)in_sizes; (void)n_in; (void)out_size; (void)ws_size;
    const float* x    = (const float*)d_in[0];
    const float* skip = (const float*)d_in[1];
    const float* Wq   = (const float*)d_in[2];
    const float* bq   = (const float*)d_in[3];
    const float* Wk   = (const float*)d_in[4];
    const float* bk   = (const float*)d_in[5];
    const float* Wv   = (const float*)d_in[6];
    const float* bv   = (const float*)d_in[7];
    const float* Wo   = (const float*)d_in[8];
    const float* bo   = (const float*)d_in[9];
    float* out = (float*)d_out;

    u16* Qo  = (u16*)d_ws;                     // [B,S,C]          8 MB
    u16* Ko  = Qo  + (size_t)M * C;            // [B,S,C]          8 MB
    u16* Vo  = Ko  + (size_t)M * C;            // [B,H,DH,S]       8 MB
    u16* ctx = Vo  + (size_t)M * C;            // [B,S,C]          8 MB

    qkv_gemm<<<dim3(M / 128, 1536 / 128), 256, 0, stream>>>(
        x, Wq, Wk, Wv, bq, bk, bv, Qo, Ko, Vo);
    attn_kernel<<<dim3(512), 512, 0, stream>>>(Qo, Ko, Vo, ctx);
    out_gemm<<<dim3(M / 64, C / 128), 256, 0, stream>>>(
        ctx, Wo, bo, skip, out);
}

// Round 11
// 177.226 us; speedup vs baseline: 1.0126x; 1.0126x over previous
//
#include <hip/hip_runtime.h>
#include <hip/hip_bf16.h>

typedef unsigned short u16;
typedef unsigned int u32;

constexpr int B  = 8;
constexpr int S  = 1024;
constexpr int C  = 512;
constexpr int H  = 8;
constexpr int DH = 64;     // C / H
constexpr int M  = B * S;  // 8192 rows

typedef __attribute__((ext_vector_type(8))) short bf16x8;   // 8 bf16 = 4 VGPRs
typedef __attribute__((ext_vector_type(4))) float f32x4;    // MFMA C/D

#define GLOBAL_AS __attribute__((address_space(1)))
#define LDS_AS    __attribute__((address_space(3)))

// 0.125 (1/sqrt(DH)) * log2(e): QK^T softmax runs in the exp2 domain.
#define QSCALE 0.1803368867f

__device__ __forceinline__ u16 f2bf(float f) {
    u32 u = __float_as_uint(f);
    u += 0x7fffu + ((u >> 16) & 1u);
    return (u16)(u >> 16);
}
__device__ __forceinline__ void async_cp16(const u16* g, u16* l) {
    __builtin_amdgcn_global_load_lds((const GLOBAL_AS void*)g, (LDS_AS void*)l, 16, 0, 0);
}
// load 8 f32 from g, convert to 8 bf16 (RNE, packed cvt), store 16 B to LDS
__device__ __forceinline__ void cvt_store8(u16* lds, const float* g) {
    const float4 a = *(const float4*)g;
    const float4 b = *(const float4*)(g + 4);
    __hip_bfloat162 p0 = __float22bfloat162_rn(make_float2(a.x, a.y));
    __hip_bfloat162 p1 = __float22bfloat162_rn(make_float2(a.z, a.w));
    __hip_bfloat162 p2 = __float22bfloat162_rn(make_float2(b.x, b.y));
    __hip_bfloat162 p3 = __float22bfloat162_rn(make_float2(b.z, b.w));
    uint4 o;
    o.x = *reinterpret_cast<u32*>(&p0);
    o.y = *reinterpret_cast<u32*>(&p1);
    o.z = *reinterpret_cast<u32*>(&p2);
    o.w = *reinterpret_cast<u32*>(&p3);
    *(uint4*)lds = o;
}

// ---------------------------------------------------------------------------
// Fused QKV MFMA GEMM, 64x128 tile, grid (128,12)=1536 blocks (6/CU).
// Two-barrier structure; f32 inputs converted to bf16 during staging.
// LDS uses the attn-proven XOR chunk swizzle (cc ^ row&7, 16-B granularity)
// on both staging writes and fragment reads -> conflict-free, no padding.
// N-tiles 0..3 -> Q, 4..7 -> K, 8..11 -> V; Q epilogue folds QSCALE.
// Epilogues re-block through LDS, coalesced dwordx4 stores:
//   Q,K -> [B,S,C]; V -> [B,H,DH,S].
// ---------------------------------------------------------------------------
__global__ __launch_bounds__(256) void qkv_gemm(
    const float* __restrict__ x,
    const float* __restrict__ wq, const float* __restrict__ wk,
    const float* __restrict__ wv,
    const float* __restrict__ bq, const float* __restrict__ bk,
    const float* __restrict__ bv,
    u16* __restrict__ Qo, u16* __restrict__ Ko, u16* __restrict__ Vo)
{
    __shared__ alignas(16) u16 smem[12288];       // 24 KB: Asm 4K u16 | Bsm 8K u16
    u16* const Asm = smem;                        // [64][64]  swizzled
    u16* const Bsm = smem + 64 * 64;              // [128][64] swizzled

    const int mTile = blockIdx.x * 64;
    const int nTile = blockIdx.y * 128;           // within 1536
    const int t = threadIdx.x, lane = t & 63, w = t >> 6;
    const int ql = lane & 15, quad = lane >> 4;
    const int wm = (w & 1) * 32, wn = (w >> 1) * 64;

    const int z = nTile >> 9;                     // 0:Q 1:K 2:V (block-uniform)
    const int nBase = nTile & 511;
    const float* Wsrc = (z == 0) ? wq : (z == 1) ? wk : wv;

    // swizzled 16B-chunk offsets for fragment reads (row&7 == ql&7)
    const int swzA = ((quad       ^ (ql & 7)) << 3);
    const int swzB = (((quad + 4) ^ (ql & 7)) << 3);

    f32x4 acc[2][4];
    #pragma unroll
    for (int i = 0; i < 2; i++)
        #pragma unroll
        for (int j = 0; j < 4; j++) acc[i][j] = (f32x4){0.f, 0.f, 0.f, 0.f};

    for (int k0 = 0; k0 < C; k0 += 64) {
        __syncthreads();
        // A: 64x64 -> 512 chunks (2/thread); B: 128x64 -> 1024 chunks (4/thread)
        #pragma unroll
        for (int q = 0; q < 2; q++) {
            const int c = q * 256 + t;
            const int row = c >> 3, cc = c & 7;
            const int sc8 = ((cc ^ (row & 7)) << 3);
            cvt_store8(&Asm[row * 64 + sc8], x + (size_t)(mTile + row) * C + k0 + cc*8);
        }
        #pragma unroll
        for (int q = 0; q < 4; q++) {
            const int c = q * 256 + t;
            const int row = c >> 3, cc = c & 7;
            const int sc8 = ((cc ^ (row & 7)) << 3);
            cvt_store8(&Bsm[row * 64 + sc8], Wsrc + (size_t)(nBase + row) * C + k0 + cc*8);
        }
        __syncthreads();

        #pragma unroll
        for (int ks = 0; ks < 2; ks++) {
            const int swz = (ks == 0) ? swzA : swzB;
            bf16x8 af[2], bfr[4];
            #pragma unroll
            for (int i = 0; i < 2; i++)
                af[i] = *(const bf16x8*)&Asm[(wm + i*16 + ql) * 64 + swz];
            #pragma unroll
            for (int j = 0; j < 4; j++)
                bfr[j] = *(const bf16x8*)&Bsm[(wn + j*16 + ql) * 64 + swz];
            #pragma unroll
            for (int i = 0; i < 2; i++)
                #pragma unroll
                for (int j = 0; j < 4; j++)
                    acc[i][j] = __builtin_amdgcn_mfma_f32_16x16x32_bf16(af[i], bfr[j], acc[i][j], 0, 0, 0);
        }
    }

    const float* bias = (z == 0) ? bq : (z == 1) ? bk : bv;
    const float sc    = (z == 0) ? QSCALE : 1.0f;

    // ---- fragments -> LDS tile (Q,K: [m][n] stride 136; V: [n][m] stride 72)
    __syncthreads();                             // done with Asm/Bsm
    u16* const T = smem;                         // <= 18432 B, fits 24 KB
    #pragma unroll
    for (int j = 0; j < 4; j++) {
        const int n = wn + j*16 + ql;
        const float bj = bias[nBase + n];
        #pragma unroll
        for (int i = 0; i < 2; i++) {
            #pragma unroll
            for (int r = 0; r < 4; r++) {
                const int m = wm + i*16 + quad*4 + r;
                const u16 val = f2bf((acc[i][j][r] + bj) * sc);
                if (z == 2) T[n * 72 + m] = val;
                else        T[m * 136 + n] = val;
            }
        }
    }
    __syncthreads();

    // ---- coalesced dwordx4 stores (4 chunks/thread)
    if (z == 2) {
        const int bb = mTile >> 10, ssBase = mTile & 1023;
        #pragma unroll
        for (int q = 0; q < 4; q++) {
            const int c = q * 256 + t;           // 0..1023 16B chunks
            const int row = c >> 3, col = (c & 7) * 8;      // row=n, col=m(s)
            const int o = nBase + row, h = o >> 6, d = o & 63;
            *(float4*)(Vo + ((size_t)((bb*H + h) * DH + d)) * S + ssBase + col) =
                *(const float4*)&T[row * 72 + col];
        }
    } else {
        u16* dst = (z == 0) ? Qo : Ko;
        #pragma unroll
        for (int q = 0; q < 4; q++) {
            const int c = q * 256 + t;           // 0..1023 16B chunks
            const int row = c >> 4, col = (c & 15) * 8;     // row=m, col=n
            *(float4*)(dst + (size_t)(mTile + row) * C + nBase + col) =
                *(const float4*)&T[row * 136 + col];
        }
    }
}

// ---------------------------------------------------------------------------
// MFMA flash attention (exact proven R8/R10 version). 512 threads = 8 waves
// per block, 128 q-rows per block; grid 512, XCD-swizzled. K/V tiles staged
// by global_load_lds with GLOBAL-side XOR chunk swizzle. No-max exp2
// softmax; denominator via ones-column MFMA. Two barriers per k-tile.
// ---------------------------------------------------------------------------
__global__ __launch_bounds__(512) void attn_kernel(
    const u16* __restrict__ Qo,   // [B,S,C]  (pre-scaled by QSCALE)
    const u16* __restrict__ Ko,   // [B,S,C]
    const u16* __restrict__ Vo,   // [B,H,DH,S]
    u16* __restrict__ ctx)        // [B,S,C] bf16
{
    __shared__ alignas(16) u16 KsU[64 * 64];    // [key][d], global-XOR-swizzled
    __shared__ alignas(16) u16 VsU[64 * 64];    // [d][key], global-XOR-swizzled
    __shared__ alignas(16) u16 Ps [128 * 72];   // [q][key], stride 72 (padded)

    const int g = blockIdx.x;            // 0..511
    const int xcd = g & 7, slot = g >> 3;       // slot 0..63
    const int bh = xcd * 8 + (slot >> 3);       // 8 heads per XCD
    const int qt = slot & 7;                    // 128-row q tile
    const int b_ = bh >> 3, h = bh & 7;

    const int t = threadIdx.x;
    const int lane = t & 63, w = t >> 6;        // w 0..7
    const int ql = lane & 15, quad = lane >> 4;

    const u16* Qb = Qo + (size_t)b_ * S * C + h * DH;   // row stride C
    const u16* Kb = Ko + (size_t)b_ * S * C + h * DH;   // row stride C
    const u16* Vt = Vo + (size_t)bh * DH * S;

    const int qrow = qt*128 + w*16 + ql;
    const bf16x8 qf0 = *(const bf16x8*)(Qb + (size_t)qrow * C + quad*8);
    const bf16x8 qf1 = *(const bf16x8*)(Qb + (size_t)qrow * C + 32 + quad*8);

    bf16x8 onesf;
    #pragma unroll
    for (int i = 0; i < 8; i++) onesf[i] = (short)0x3F80;   // bf16 1.0

    // swizzled chunk offsets for fragment reads (row&7 == ql&7 for all reads)
    const int swzA = ((quad       ^ (ql & 7)) << 3);   // cc = quad
    const int swzB = (((quad + 4) ^ (ql & 7)) << 3);   // cc = quad + 4

    // staging: thread t handles 16B chunk t of K and of V; DMA LDS dest is
    // linear (chunk*16B); the XOR swizzle is applied to the GLOBAL chunk.
    const int srow = t >> 3, scc = t & 7;
    const int sgc8 = ((scc ^ (srow & 7)) << 3);        // swizzled global column

    f32x4 acc[4], accl;
    #pragma unroll
    for (int dt = 0; dt < 4; dt++) acc[dt] = (f32x4){0.f, 0.f, 0.f, 0.f};
    accl = (f32x4){0.f, 0.f, 0.f, 0.f};

    for (int k0 = 0; k0 < S; k0 += 64) {
        __syncthreads();
        async_cp16(Kb + (size_t)(k0 + srow) * C + sgc8, &KsU[t * 8]);
        async_cp16(Vt + (size_t)srow * S + k0 + sgc8,   &VsU[t * 8]);
        __syncthreads();

        // ---- QK^T (exp2-scaled via Q)
        f32x4 sc[4];
        #pragma unroll
        for (int nt = 0; nt < 4; nt++) {
            sc[nt] = (f32x4){0.f, 0.f, 0.f, 0.f};
            const bf16x8 kf0 = *(const bf16x8*)&KsU[(nt*16 + ql) * 64 + swzA];
            const bf16x8 kf1 = *(const bf16x8*)&KsU[(nt*16 + ql) * 64 + swzB];
            sc[nt] = __builtin_amdgcn_mfma_f32_16x16x32_bf16(qf0, kf0, sc[nt], 0, 0, 0);
            sc[nt] = __builtin_amdgcn_mfma_f32_16x16x32_bf16(qf1, kf1, sc[nt], 0, 0, 0);
        }

        // ---- softmax numerators: p = exp2(s), no max subtraction
        #pragma unroll
        for (int r = 0; r < 4; r++) {
            const int prow = w*16 + quad*4 + r;
            Ps[prow * 72 +  0 + ql] = f2bf(exp2f(sc[0][r]));
            Ps[prow * 72 + 16 + ql] = f2bf(exp2f(sc[1][r]));
            Ps[prow * 72 + 32 + ql] = f2bf(exp2f(sc[2][r]));
            Ps[prow * 72 + 48 + ql] = f2bf(exp2f(sc[3][r]));
        }

        // ---- PV + denominator (wave-private Ps stripe, wave-synchronous)
        #pragma unroll
        for (int c = 0; c < 2; c++) {
            const bf16x8 pf = *(const bf16x8*)&Ps[(w*16 + ql) * 72 + c*32 + quad*8];
            const int swz = (c == 0) ? swzA : swzB;
            #pragma unroll
            for (int dt = 0; dt < 4; dt++) {
                const bf16x8 vf = *(const bf16x8*)&VsU[(dt*16 + ql) * 64 + swz];
                acc[dt] = __builtin_amdgcn_mfma_f32_16x16x32_bf16(pf, vf, acc[dt], 0, 0, 0);
            }
            accl = __builtin_amdgcn_mfma_f32_16x16x32_bf16(pf, onesf, accl, 0, 0, 0);
        }
    }

    #pragma unroll
    for (int r = 0; r < 4; r++) {
        const float inv = 1.0f / accl[r];
        const int orow = qt*128 + w*16 + quad*4 + r;
        const size_t base = ((size_t)(b_*S + orow)) * C + h*DH;
        #pragma unroll
        for (int dt = 0; dt < 4; dt++)
            ctx[base + dt*16 + ql] = f2bf(acc[dt][r] * inv);
    }
}

// ---------------------------------------------------------------------------
// Output-projection MFMA GEMM (exact R10 version): out = ctx @ Wo^T + bo +
// skip. 64x128 tile -> grid 512, two-barrier single-buffer staging.
// A (ctx, bf16) via global_load_lds DMA; B (Wo, f32) converted in staging.
// ---------------------------------------------------------------------------
__global__ __launch_bounds__(256) void out_gemm(
    const u16* __restrict__ ctx, const float* __restrict__ wo,
    const float* __restrict__ bo, const float* __restrict__ skip,
    float* __restrict__ out)
{
    __shared__ alignas(16) u16 Ab[64 * 64];     // 8 KB
    __shared__ alignas(16) u16 Bb[128 * 64];    // 16 KB

    const int mTile = blockIdx.x * 64;
    const int nTile = blockIdx.y * 128;
    const int t = threadIdx.x, lane = t & 63, w = t >> 6;
    const int ql = lane & 15, quad = lane >> 4;
    const int wm = (w & 1) * 32, wn = (w >> 1) * 64;

    f32x4 acc[2][4];
    #pragma unroll
    for (int i = 0; i < 2; i++)
        #pragma unroll
        for (int j = 0; j < 4; j++) acc[i][j] = (f32x4){0.f, 0.f, 0.f, 0.f};

    for (int k0 = 0; k0 < C; k0 += 64) {
        __syncthreads();
        #pragma unroll
        for (int q = 0; q < 2; q++) {            // A: 512 chunks (bf16 DMA)
            const int chunk = q * 256 + t;
            const int row = chunk >> 3, c8 = (chunk & 7) * 8;
            async_cp16(ctx + (size_t)(mTile + row) * C + k0 + c8, &Ab[chunk * 8]);
        }
        #pragma unroll
        for (int q = 0; q < 4; q++) {            // B: 1024 chunks (f32 -> bf16)
            const int chunk = q * 256 + t;
            const int row = chunk >> 3, c8 = (chunk & 7) * 8;
            cvt_store8(&Bb[chunk * 8], wo + (size_t)(nTile + row) * C + k0 + c8);
        }
        __syncthreads();

        #pragma unroll
        for (int ks = 0; ks < 64; ks += 32) {
            bf16x8 af[2], bfr[4];
            #pragma unroll
            for (int i = 0; i < 2; i++)
                af[i] = *(const bf16x8*)&Ab[(wm + i*16 + ql) * 64 + ks + quad*8];
            #pragma unroll
            for (int j = 0; j < 4; j++)
                bfr[j] = *(const bf16x8*)&Bb[(wn + j*16 + ql) * 64 + ks + quad*8];
            #pragma unroll
            for (int i = 0; i < 2; i++)
                #pragma unroll
                for (int j = 0; j < 4; j++)
                    acc[i][j] = __builtin_amdgcn_mfma_f32_16x16x32_bf16(af[i], bfr[j], acc[i][j], 0, 0, 0);
        }
    }

    #pragma unroll
    for (int j = 0; j < 4; j++) {
        const int o = nTile + wn + j*16 + ql;
        const float bj = bo[o];
        #pragma unroll
        for (int i = 0; i < 2; i++) {
            #pragma unroll
            for (int r = 0; r < 4; r++) {
                const int m = mTile + wm + i*16 + quad*4 + r;
                const size_t idx = (size_t)m * C + o;
                out[idx] = acc[i][j][r] + bj + skip[idx];
            }
        }
    }
}

extern "C" void kernel_launch(void* const* d_in, const int* in_sizes, int n_in,
                              void* d_out, int out_size, void* d_ws, size_t ws_size,
                              hipStream_t stream) {
    (void)in_sizes; (void)n_in; (void)out_size; (void)ws_size;
    const float* x    = (const float*)d_in[0];
    const float* skip = (const float*)d_in[1];
    const float* Wq   = (const float*)d_in[2];
    const float* bq   = (const float*)d_in[3];
    const float* Wk   = (const float*)d_in[4];
    const float* bk   = (const float*)d_in[5];
    const float* Wv   = (const float*)d_in[6];
    const float* bv   = (const float*)d_in[7];
    const float* Wo   = (const float*)d_in[8];
    const float* bo   = (const float*)d_in[9];
    float* out = (float*)d_out;

    u16* Qo  = (u16*)d_ws;                     // [B,S,C]          8 MB
    u16* Ko  = Qo  + (size_t)M * C;            // [B,S,C]          8 MB
    u16* Vo  = Ko  + (size_t)M * C;            // [B,H,DH,S]       8 MB
    u16* ctx = Vo  + (size_t)M * C;            // [B,S,C]          8 MB

    qkv_gemm<<<dim3(M / 64, 1536 / 128), 256, 0, stream>>>(
        x, Wq, Wk, Wv, bq, bk, bv, Qo, Ko, Vo);
    attn_kernel<<<dim3(512), 512, 0, stream>>>(Qo, Ko, Vo, ctx);
    out_gemm<<<dim3(M / 64, C / 128), 256, 0, stream>>>(
        ctx, Wo, bo, skip, out);
}